// Round 2
// baseline (2007.651 us; speedup 1.0000x reference)
//
#include <hip/hip_runtime.h>
#include <math.h>

#define N_NODES 200000
#define N_EDGES 6400000
#define N_GRAPHS 2048
#define HID 32
#define BN_EPS 1e-5f

#define SCAN_TPB 256
#define SCAN_EPT 8
#define SCAN_EPB (SCAN_TPB * SCAN_EPT)

__device__ inline float relu_f(float v) { return fmaxf(v, 0.f); }

// ---------------- degree count ----------------
__global__ void k_deg(const int* __restrict__ dst, int* __restrict__ deg) {
    int e = blockIdx.x * blockDim.x + threadIdx.x;
    if (e < N_EDGES) atomicAdd(&deg[dst[e]], 1);
}

// ---------------- exclusive scan (3 kernels) ----------------
__global__ void k_scan_partial(const int* __restrict__ deg, int* __restrict__ bsum) {
    int base = blockIdx.x * SCAN_EPB;
    int s = 0;
    for (int i = threadIdx.x; i < SCAN_EPB; i += SCAN_TPB) {
        int idx = base + i;
        if (idx < N_NODES) s += deg[idx];
    }
    for (int o = 32; o; o >>= 1) s += __shfl_down(s, o);
    __shared__ int ws[SCAN_TPB / 64];
    if ((threadIdx.x & 63) == 0) ws[threadIdx.x >> 6] = s;
    __syncthreads();
    if (threadIdx.x == 0) {
        int t = 0;
        for (int i = 0; i < SCAN_TPB / 64; i++) t += ws[i];
        bsum[blockIdx.x] = t;
    }
}

__global__ void k_scan_bases(const int* __restrict__ bsum, int* __restrict__ bbase,
                             int nb, int* __restrict__ offsets) {
    if (threadIdx.x == 0 && blockIdx.x == 0) {
        int acc = 0;
        for (int b = 0; b < nb; b++) { bbase[b] = acc; acc += bsum[b]; }
        offsets[N_NODES] = acc;
    }
}

__global__ void k_scan_write(const int* __restrict__ deg, const int* __restrict__ bbase,
                             int* __restrict__ offsets) {
    __shared__ int tsum[SCAN_TPB];
    int t = threadIdx.x;
    int base = blockIdx.x * SCAN_EPB + t * SCAN_EPT;
    int v[SCAN_EPT];
    int s = 0;
#pragma unroll
    for (int i = 0; i < SCAN_EPT; i++) {
        int idx = base + i;
        v[i] = (idx < N_NODES) ? deg[idx] : 0;
        s += v[i];
    }
    tsum[t] = s;
    __syncthreads();
    for (int off = 1; off < SCAN_TPB; off <<= 1) {
        int y = (t >= off) ? tsum[t - off] : 0;
        __syncthreads();
        tsum[t] += y;
        __syncthreads();
    }
    int run = bbase[blockIdx.x] + tsum[t] - s;
#pragma unroll
    for (int i = 0; i < SCAN_EPT; i++) {
        int idx = base + i;
        if (idx < N_NODES) offsets[idx] = run;
        run += v[i];
    }
}

// ---------------- CSR scatter + conv1 neighbor sums ----------------
__global__ void k_scatter(const int* __restrict__ src, const int* __restrict__ dst,
                          const float* __restrict__ x, const int* __restrict__ offsets,
                          int* __restrict__ cnt, int* __restrict__ csr,
                          float* __restrict__ sum1) {
    int e = blockIdx.x * blockDim.x + threadIdx.x;
    if (e < N_EDGES) {
        int s = src[e], d = dst[e];
        atomicAdd(&sum1[d], x[s]);
        int pos = atomicAdd(&cnt[d], 1);
        csr[offsets[d] + pos] = s;
    }
}

// ---------------- BN1 scalar stats (a = mean-neighbor-x) ----------------
__global__ void k_stats1(const int* __restrict__ deg, const float* __restrict__ sum1,
                         const float* __restrict__ x, float* __restrict__ a,
                         double* __restrict__ stats1) {
    int n = blockIdx.x * blockDim.x + threadIdx.x;
    float an = 0.f, xn = 0.f;
    if (n < N_NODES) {
        int dg = deg[n];
        an = sum1[n] / (float)max(dg, 1);
        a[n] = an;
        xn = x[n];
    }
    float sa = an, sx = xn, saa = an * an, sxx = xn * xn, sax = an * xn;
    for (int o = 32; o; o >>= 1) {
        sa += __shfl_down(sa, o);
        sx += __shfl_down(sx, o);
        saa += __shfl_down(saa, o);
        sxx += __shfl_down(sxx, o);
        sax += __shfl_down(sax, o);
    }
    if ((threadIdx.x & 63) == 0) {
        atomicAdd(&stats1[0], (double)sa);
        atomicAdd(&stats1[1], (double)sx);
        atomicAdd(&stats1[2], (double)saa);
        atomicAdd(&stats1[3], (double)sxx);
        atomicAdd(&stats1[4], (double)sax);
    }
}

// ---------------- fold BN1 into affine h1 = relu(a*A + x*B + C) ----------------
__global__ void k_params1(const double* __restrict__ stats1,
                          const float* __restrict__ W1l, const float* __restrict__ b1l,
                          const float* __restrict__ W1r, const float* __restrict__ g1,
                          const float* __restrict__ be1, float* __restrict__ pABC) {
    int f = threadIdx.x;
    if (f < HID) {
        double invN = 1.0 / (double)N_NODES;
        double ma = stats1[0] * invN, mx = stats1[1] * invN;
        double va = stats1[2] * invN - ma * ma;
        double vx = stats1[3] * invN - mx * mx;
        double cax = stats1[4] * invN - ma * mx;
        double wl = (double)W1l[f], wr = (double)W1r[f];
        double mu = wl * ma + wr * mx + (double)b1l[f];
        double var = wl * wl * va + wr * wr * vx + 2.0 * wl * wr * cax;
        double s = (double)g1[f] / sqrt(var + (double)BN_EPS);
        pABC[f] = (float)(wl * s);
        pABC[HID + f] = (float)(wr * s);
        pABC[2 * HID + f] = (float)(((double)b1l[f] - mu) * s + (double)be1[f]);
    }
}

// ---------------- conv2 aggregation: 32 lanes per node, recompute h1[src] ----------------
__global__ void k_agg2(const int* __restrict__ offsets, const int* __restrict__ deg,
                       const int* __restrict__ csr, const float* __restrict__ a,
                       const float* __restrict__ x, const float* __restrict__ pABC,
                       float* __restrict__ agg2) {
    int t = blockIdx.x * blockDim.x + threadIdx.x;
    int node = t >> 5, f = t & 31;
    if (node >= N_NODES) return;
    float Af = pABC[f], Bf = pABC[HID + f], Cf = pABC[2 * HID + f];
    int beg = offsets[node];
    int dg = deg[node];
    float m = 0.f;
    for (int j = beg; j < beg + dg; j++) {
        int s = csr[j];
        float as = a[s];
        float xs = x[s];
        m += relu_f(fmaf(as, Af, fmaf(xs, Bf, Cf)));
    }
    agg2[(size_t)node * HID + f] = m / (float)max(dg, 1);
}

// ---------------- conv2 matmul + BN2 stats: thread per node ----------------
__launch_bounds__(256)
__global__ void k_mm(const float* __restrict__ a, const float* __restrict__ x,
                     const float* __restrict__ agg2, const float* __restrict__ pABC,
                     const float* __restrict__ W2l, const float* __restrict__ W2r,
                     const float* __restrict__ b2l, float* __restrict__ h2pre,
                     double* __restrict__ stats2) {
    __shared__ float Wl_s[HID * HID], Wr_s[HID * HID];
    __shared__ float A_s[HID], B_s[HID], C_s[HID], bb_s[HID];
    for (int i = threadIdx.x; i < HID * HID; i += blockDim.x) {
        Wl_s[i] = W2l[i];
        Wr_s[i] = W2r[i];
    }
    if (threadIdx.x < HID) {
        A_s[threadIdx.x] = pABC[threadIdx.x];
        B_s[threadIdx.x] = pABC[HID + threadIdx.x];
        C_s[threadIdx.x] = pABC[2 * HID + threadIdx.x];
        bb_s[threadIdx.x] = b2l[threadIdx.x];
    }
    __syncthreads();
    int n = blockIdx.x * blockDim.x + threadIdx.x;
    bool valid = (n < N_NODES);
    int nn = valid ? n : (N_NODES - 1);
    float an = a[nn], xn = x[nn];
    float h1[HID];
#pragma unroll
    for (int f = 0; f < HID; f++)
        h1[f] = relu_f(fmaf(an, A_s[f], fmaf(xn, B_s[f], C_s[f])));
    float ag[HID];
    const float4* ap = (const float4*)(agg2 + (size_t)nn * HID);
#pragma unroll
    for (int i = 0; i < HID / 4; i++) {
        float4 v = ap[i];
        ag[4 * i] = v.x; ag[4 * i + 1] = v.y; ag[4 * i + 2] = v.z; ag[4 * i + 3] = v.w;
    }
    float msk = valid ? 1.f : 0.f;
#pragma unroll 2
    for (int f = 0; f < HID; f++) {
        float v = bb_s[f];
#pragma unroll
        for (int k = 0; k < HID; k++)
            v = fmaf(ag[k], Wl_s[f * HID + k], fmaf(h1[k], Wr_s[f * HID + k], v));
        if (valid) h2pre[(size_t)n * HID + f] = v;
        float s1v = v * msk, s2v = v * v * msk;
        for (int o = 32; o; o >>= 1) {
            s1v += __shfl_down(s1v, o);
            s2v += __shfl_down(s2v, o);
        }
        if ((threadIdx.x & 63) == 0) {
            atomicAdd(&stats2[f], (double)s1v);
            atomicAdd(&stats2[HID + f], (double)s2v);
        }
    }
}

// ---------------- fold BN2 ----------------
__global__ void k_params2(const double* __restrict__ stats2, const float* __restrict__ g2,
                          const float* __restrict__ be2, float* __restrict__ pPQ) {
    int f = threadIdx.x;
    if (f < HID) {
        double invN = 1.0 / (double)N_NODES;
        double mu = stats2[f] * invN;
        double var = stats2[HID + f] * invN - mu * mu;
        double s = (double)g2[f] / sqrt(var + (double)BN_EPS);
        pPQ[f] = (float)s;
        pPQ[HID + f] = (float)((double)be2[f] - mu * s);
    }
}

// ---------------- attentional pooling: block per graph ----------------
#define FIN_TPB 128
__launch_bounds__(FIN_TPB)
__global__ void k_final(const float* __restrict__ h2pre, const int* __restrict__ batch,
                        const float* __restrict__ pPQ, const float* __restrict__ gate_w,
                        const float* __restrict__ gate_b, const float* __restrict__ lin_w,
                        const float* __restrict__ lin_b, float* __restrict__ out) {
    __shared__ int sh_lo, sh_hi;
    __shared__ float red[2][HID + 2];
    __shared__ float sh_P[HID], sh_Q[HID], sh_gw[HID], sh_lw[HID];
    int g = blockIdx.x;
    if (threadIdx.x == 0) {
        int lo = 0, hi = N_NODES;
        while (lo < hi) { int mid = (lo + hi) >> 1; if (batch[mid] < g) lo = mid + 1; else hi = mid; }
        sh_lo = lo;
        int lo2 = lo, hi2 = N_NODES;
        int key2 = g + 1;
        while (lo2 < hi2) { int mid = (lo2 + hi2) >> 1; if (batch[mid] < key2) lo2 = mid + 1; else hi2 = mid; }
        sh_hi = lo2;
    }
    if (threadIdx.x < HID) {
        sh_P[threadIdx.x] = pPQ[threadIdx.x];
        sh_Q[threadIdx.x] = pPQ[HID + threadIdx.x];
        sh_gw[threadIdx.x] = gate_w[threadIdx.x];
        sh_lw[threadIdx.x] = lin_w[threadIdx.x];
    }
    __syncthreads();
    int lo = sh_lo, hi = sh_hi;
    float gb = gate_b[0];

    // pass 1: segment max of gate score
    float mx = -3.0e38f;
    for (int n = lo + threadIdx.x; n < hi; n += FIN_TPB) {
        const float4* hp = (const float4*)(h2pre + (size_t)n * HID);
        float sc = gb;
#pragma unroll
        for (int i = 0; i < HID / 4; i++) {
            float4 v = hp[i];
            sc += relu_f(fmaf(v.x, sh_P[4 * i], sh_Q[4 * i])) * sh_gw[4 * i];
            sc += relu_f(fmaf(v.y, sh_P[4 * i + 1], sh_Q[4 * i + 1])) * sh_gw[4 * i + 1];
            sc += relu_f(fmaf(v.z, sh_P[4 * i + 2], sh_Q[4 * i + 2])) * sh_gw[4 * i + 2];
            sc += relu_f(fmaf(v.w, sh_P[4 * i + 3], sh_Q[4 * i + 3])) * sh_gw[4 * i + 3];
        }
        mx = fmaxf(mx, sc);
    }
    for (int o = 32; o; o >>= 1) mx = fmaxf(mx, __shfl_down(mx, o));
    if ((threadIdx.x & 63) == 0) red[threadIdx.x >> 6][0] = mx;
    __syncthreads();
    float smax = fmaxf(red[0][0], red[1][0]);
    __syncthreads();

    // pass 2: exp-sum and weighted feature sums
    float S = 0.f;
    float T[HID];
#pragma unroll
    for (int f = 0; f < HID; f++) T[f] = 0.f;
    for (int n = lo + threadIdx.x; n < hi; n += FIN_TPB) {
        const float4* hp = (const float4*)(h2pre + (size_t)n * HID);
        float h[HID];
        float sc = gb;
#pragma unroll
        for (int i = 0; i < HID / 4; i++) {
            float4 v = hp[i];
            h[4 * i]     = relu_f(fmaf(v.x, sh_P[4 * i],     sh_Q[4 * i]));
            h[4 * i + 1] = relu_f(fmaf(v.y, sh_P[4 * i + 1], sh_Q[4 * i + 1]));
            h[4 * i + 2] = relu_f(fmaf(v.z, sh_P[4 * i + 2], sh_Q[4 * i + 2]));
            h[4 * i + 3] = relu_f(fmaf(v.w, sh_P[4 * i + 3], sh_Q[4 * i + 3]));
            sc += h[4 * i] * sh_gw[4 * i] + h[4 * i + 1] * sh_gw[4 * i + 1]
                + h[4 * i + 2] * sh_gw[4 * i + 2] + h[4 * i + 3] * sh_gw[4 * i + 3];
        }
        float e = __expf(sc - smax);
        S += e;
#pragma unroll
        for (int f = 0; f < HID; f++) T[f] += e * h[f];
    }
    for (int o = 32; o; o >>= 1) {
        S += __shfl_down(S, o);
#pragma unroll
        for (int f = 0; f < HID; f++) T[f] += __shfl_down(T[f], o);
    }
    if ((threadIdx.x & 63) == 0) {
        int w = threadIdx.x >> 6;
        red[w][1] = S;
#pragma unroll
        for (int f = 0; f < HID; f++) red[w][2 + f] = T[f];
    }
    __syncthreads();
    if (threadIdx.x == 0) {
        float St = red[0][1] + red[1][1];
        float z = lin_b[0];
        if (St > 0.f) {
            float inv = 1.f / St;
#pragma unroll
            for (int f = 0; f < HID; f++)
                z += (red[0][2 + f] + red[1][2 + f]) * inv * sh_lw[f];
        }
        out[g] = 1.f / (1.f + __expf(-z));
    }
}

extern "C" void kernel_launch(void* const* d_in, const int* in_sizes, int n_in,
                              void* d_out, int out_size, void* d_ws, size_t ws_size,
                              hipStream_t stream) {
    const float* x = (const float*)d_in[0];
    const int* ei = (const int*)d_in[1];       // int32 per harness convention
    const int* batch = (const int*)d_in[2];    // int32
    const float* W1l = (const float*)d_in[3];
    const float* b1l = (const float*)d_in[4];
    const float* W1r = (const float*)d_in[5];
    const float* W2l = (const float*)d_in[6];
    const float* b2l = (const float*)d_in[7];
    const float* W2r = (const float*)d_in[8];
    const float* g1 = (const float*)d_in[9];
    const float* be1 = (const float*)d_in[10];
    const float* g2 = (const float*)d_in[11];
    const float* be2 = (const float*)d_in[12];
    const float* gate_w = (const float*)d_in[13];
    const float* gate_b = (const float*)d_in[14];
    const float* lin_w = (const float*)d_in[15];
    const float* lin_b = (const float*)d_in[16];

    const int* srcp = ei;
    const int* dstp = ei + N_EDGES;

    char* ws = (char*)d_ws;
    size_t p = 0;
    auto alloc = [&](size_t bytes) -> char* {
        char* r = ws + p;
        p = (p + bytes + 255) & ~(size_t)255;
        return r;
    };
    // zero-initialized region (one memset covers [0, zbytes))
    int* deg = (int*)alloc((size_t)N_NODES * 4);
    int* cnt = (int*)alloc((size_t)N_NODES * 4);
    float* sum1 = (float*)alloc((size_t)N_NODES * 4);
    double* stats1 = (double*)alloc(8 * 8);
    double* stats2 = (double*)alloc(64 * 8);
    size_t zbytes = p;
    // non-zeroed scratch (fully written each launch)
    int* offsets = (int*)alloc((size_t)(N_NODES + 1) * 4);
    float* a = (float*)alloc((size_t)N_NODES * 4);
    float* pABC = (float*)alloc(96 * 4);
    float* pPQ = (float*)alloc(64 * 4);
    int nb = (N_NODES + SCAN_EPB - 1) / SCAN_EPB;
    int* bsum = (int*)alloc((size_t)nb * 4);
    int* bbase = (int*)alloc((size_t)nb * 4);
    float* agg2 = (float*)alloc((size_t)N_NODES * HID * 4);
    int* csr = (int*)alloc((size_t)N_EDGES * 4);
    float* h2pre = (float*)csr;  // alias: csr (E*4 B) dead before h2pre (N*HID*4 B) is written

    hipMemsetAsync(d_ws, 0, zbytes, stream);

    k_deg<<<(N_EDGES + 255) / 256, 256, 0, stream>>>(dstp, deg);
    k_scan_partial<<<nb, SCAN_TPB, 0, stream>>>(deg, bsum);
    k_scan_bases<<<1, 64, 0, stream>>>(bsum, bbase, nb, offsets);
    k_scan_write<<<nb, SCAN_TPB, 0, stream>>>(deg, bbase, offsets);
    k_scatter<<<(N_EDGES + 255) / 256, 256, 0, stream>>>(srcp, dstp, x, offsets, cnt, csr, sum1);
    k_stats1<<<(N_NODES + 255) / 256, 256, 0, stream>>>(deg, sum1, x, a, stats1);
    k_params1<<<1, 64, 0, stream>>>(stats1, W1l, b1l, W1r, g1, be1, pABC);
    k_agg2<<<(N_NODES * HID + 255) / 256, 256, 0, stream>>>(offsets, deg, csr, a, x, pABC, agg2);
    k_mm<<<(N_NODES + 255) / 256, 256, 0, stream>>>(a, x, agg2, pABC, W2l, W2r, b2l, h2pre, stats2);
    k_params2<<<1, 64, 0, stream>>>(stats2, g2, be2, pPQ);
    k_final<<<N_GRAPHS, FIN_TPB, 0, stream>>>(h2pre, batch, pPQ, gate_w, gate_b, lin_w, lin_b,
                                              (float*)d_out);
}

// Round 3
// 1257.996 us; speedup vs baseline: 1.5959x; 1.5959x over previous
//
#include <hip/hip_runtime.h>
#include <math.h>

#define N_NODES 200000
#define N_EDGES 6400000
#define N_GRAPHS 2048
#define HID 32
#define BN_EPS 1e-5f

#define NB_NODE ((N_NODES + 255) / 256)

#define SCAN_TPB 256
#define SCAN_EPT 8
#define SCAN_EPB (SCAN_TPB * SCAN_EPT)

__device__ inline float relu_f(float v) { return fmaxf(v, 0.f); }

// ---------------- degree count ----------------
__global__ void k_deg(const int* __restrict__ dst, int* __restrict__ deg) {
    int e = blockIdx.x * blockDim.x + threadIdx.x;
    if (e < N_EDGES) atomicAdd(&deg[dst[e]], 1);
}

// ---------------- exclusive scan (3 kernels) ----------------
__global__ void k_scan_partial(const int* __restrict__ deg, int* __restrict__ bsum) {
    int base = blockIdx.x * SCAN_EPB;
    int s = 0;
    for (int i = threadIdx.x; i < SCAN_EPB; i += SCAN_TPB) {
        int idx = base + i;
        if (idx < N_NODES) s += deg[idx];
    }
    for (int o = 32; o; o >>= 1) s += __shfl_down(s, o);
    __shared__ int ws[SCAN_TPB / 64];
    if ((threadIdx.x & 63) == 0) ws[threadIdx.x >> 6] = s;
    __syncthreads();
    if (threadIdx.x == 0) {
        int t = 0;
        for (int i = 0; i < SCAN_TPB / 64; i++) t += ws[i];
        bsum[blockIdx.x] = t;
    }
}

__global__ void k_scan_bases(const int* __restrict__ bsum, int* __restrict__ bbase,
                             int nb, int* __restrict__ offsets) {
    if (threadIdx.x == 0 && blockIdx.x == 0) {
        int acc = 0;
        for (int b = 0; b < nb; b++) { bbase[b] = acc; acc += bsum[b]; }
        offsets[N_NODES] = acc;
    }
}

__global__ void k_scan_write(const int* __restrict__ deg, const int* __restrict__ bbase,
                             int* __restrict__ offsets, int* __restrict__ cursor) {
    __shared__ int tsum[SCAN_TPB];
    int t = threadIdx.x;
    int base = blockIdx.x * SCAN_EPB + t * SCAN_EPT;
    int v[SCAN_EPT];
    int s = 0;
#pragma unroll
    for (int i = 0; i < SCAN_EPT; i++) {
        int idx = base + i;
        v[i] = (idx < N_NODES) ? deg[idx] : 0;
        s += v[i];
    }
    tsum[t] = s;
    __syncthreads();
    for (int off = 1; off < SCAN_TPB; off <<= 1) {
        int y = (t >= off) ? tsum[t - off] : 0;
        __syncthreads();
        tsum[t] += y;
        __syncthreads();
    }
    int run = bbase[blockIdx.x] + tsum[t] - s;
#pragma unroll
    for (int i = 0; i < SCAN_EPT; i++) {
        int idx = base + i;
        if (idx < N_NODES) { offsets[idx] = run; cursor[idx] = run; }
        run += v[i];
    }
}

// ---------------- CSR scatter + conv1 neighbor sums ----------------
__global__ void k_scatter(const int* __restrict__ src, const int* __restrict__ dst,
                          const float* __restrict__ x, int* __restrict__ cursor,
                          int* __restrict__ csr, float* __restrict__ sum1) {
    int e = blockIdx.x * blockDim.x + threadIdx.x;
    if (e < N_EDGES) {
        int s = src[e], d = dst[e];
        atomicAdd(&sum1[d], x[s]);
        int pos = atomicAdd(&cursor[d], 1);
        csr[pos] = s;
    }
}

// ---------------- BN1 scalar stats (a = mean-neighbor-x) -> per-block partials ----------------
__global__ void k_stats1(const int* __restrict__ offsets, const float* __restrict__ sum1,
                         const float* __restrict__ x, float* __restrict__ a,
                         float* __restrict__ part1) {
    int n = blockIdx.x * blockDim.x + threadIdx.x;
    float an = 0.f, xn = 0.f;
    if (n < N_NODES) {
        int dg = offsets[n + 1] - offsets[n];
        an = sum1[n] / (float)max(dg, 1);
        a[n] = an;
        xn = x[n];
    }
    float sa = an, sx = xn, saa = an * an, sxx = xn * xn, sax = an * xn;
    for (int o = 32; o; o >>= 1) {
        sa += __shfl_down(sa, o);
        sx += __shfl_down(sx, o);
        saa += __shfl_down(saa, o);
        sxx += __shfl_down(sxx, o);
        sax += __shfl_down(sax, o);
    }
    __shared__ float red[4][5];
    int w = threadIdx.x >> 6;
    if ((threadIdx.x & 63) == 0) {
        red[w][0] = sa; red[w][1] = sx; red[w][2] = saa; red[w][3] = sxx; red[w][4] = sax;
    }
    __syncthreads();
    if (threadIdx.x < 5)
        part1[blockIdx.x * 8 + threadIdx.x] =
            red[0][threadIdx.x] + red[1][threadIdx.x] + red[2][threadIdx.x] + red[3][threadIdx.x];
}

// ---------------- fold BN1 into affine h1 = relu(a*A + x*B + C) ----------------
__global__ void k_params1(const float* __restrict__ part1,
                          const float* __restrict__ W1l, const float* __restrict__ b1l,
                          const float* __restrict__ W1r, const float* __restrict__ g1,
                          const float* __restrict__ be1, float* __restrict__ pABC) {
    __shared__ double st[5];
    if (threadIdx.x < 5) {
        double s = 0.0;
        for (int b = 0; b < NB_NODE; b++) s += (double)part1[b * 8 + threadIdx.x];
        st[threadIdx.x] = s;
    }
    __syncthreads();
    int f = threadIdx.x;
    if (f < HID) {
        double invN = 1.0 / (double)N_NODES;
        double ma = st[0] * invN, mx = st[1] * invN;
        double va = st[2] * invN - ma * ma;
        double vx = st[3] * invN - mx * mx;
        double cax = st[4] * invN - ma * mx;
        double wl = (double)W1l[f], wr = (double)W1r[f];
        double mu = wl * ma + wr * mx + (double)b1l[f];
        double var = wl * wl * va + wr * wr * vx + 2.0 * wl * wr * cax;
        double s = (double)g1[f] / sqrt(var + (double)BN_EPS);
        pABC[f] = (float)(wl * s);
        pABC[HID + f] = (float)(wr * s);
        pABC[2 * HID + f] = (float)(((double)b1l[f] - mu) * s + (double)be1[f]);
    }
}

// ---------------- conv2 aggregation: 32 lanes per node, recompute h1[src] ----------------
__global__ void k_agg2(const int* __restrict__ offsets, const int* __restrict__ csr,
                       const float* __restrict__ a, const float* __restrict__ x,
                       const float* __restrict__ pABC, float* __restrict__ agg2) {
    int t = blockIdx.x * blockDim.x + threadIdx.x;
    int node = t >> 5, f = t & 31;
    if (node >= N_NODES) return;
    float Af = pABC[f], Bf = pABC[HID + f], Cf = pABC[2 * HID + f];
    int beg = offsets[node];
    int end = offsets[node + 1];
    float m = 0.f;
    for (int j = beg; j < end; j++) {
        int s = csr[j];
        float as = a[s];
        float xs = x[s];
        m += relu_f(fmaf(as, Af, fmaf(xs, Bf, Cf)));
    }
    agg2[(size_t)node * HID + f] = m / (float)max(end - beg, 1);
}

// ---------------- conv2 matmul + BN2 per-block partials ----------------
__launch_bounds__(256)
__global__ void k_mm(const float* __restrict__ a, const float* __restrict__ x,
                     const float* __restrict__ agg2, const float* __restrict__ pABC,
                     const float* __restrict__ W2l, const float* __restrict__ W2r,
                     const float* __restrict__ b2l, float* __restrict__ h2pre,
                     float* __restrict__ part2) {
    __shared__ float Wl_s[HID * HID], Wr_s[HID * HID];
    __shared__ float A_s[HID], B_s[HID], C_s[HID], bb_s[HID];
    __shared__ float red[4][2 * HID];
    for (int i = threadIdx.x; i < HID * HID; i += blockDim.x) {
        Wl_s[i] = W2l[i];
        Wr_s[i] = W2r[i];
    }
    if (threadIdx.x < HID) {
        A_s[threadIdx.x] = pABC[threadIdx.x];
        B_s[threadIdx.x] = pABC[HID + threadIdx.x];
        C_s[threadIdx.x] = pABC[2 * HID + threadIdx.x];
        bb_s[threadIdx.x] = b2l[threadIdx.x];
    }
    __syncthreads();
    int n = blockIdx.x * blockDim.x + threadIdx.x;
    bool valid = (n < N_NODES);
    int nn = valid ? n : (N_NODES - 1);
    float an = a[nn], xn = x[nn];
    float h1[HID];
#pragma unroll
    for (int f = 0; f < HID; f++)
        h1[f] = relu_f(fmaf(an, A_s[f], fmaf(xn, B_s[f], C_s[f])));
    float ag[HID];
    const float4* ap = (const float4*)(agg2 + (size_t)nn * HID);
#pragma unroll
    for (int i = 0; i < HID / 4; i++) {
        float4 v = ap[i];
        ag[4 * i] = v.x; ag[4 * i + 1] = v.y; ag[4 * i + 2] = v.z; ag[4 * i + 3] = v.w;
    }
    float v[HID];
#pragma unroll 4
    for (int f = 0; f < HID; f++) {
        float s = bb_s[f];
#pragma unroll
        for (int k = 0; k < HID; k++)
            s = fmaf(ag[k], Wl_s[f * HID + k], fmaf(h1[k], Wr_s[f * HID + k], s));
        v[f] = s;
    }
    // contiguous 128B store per thread (8 x dwordx4 back-to-back -> full-line combining)
    if (valid) {
        float4* op = (float4*)(h2pre + (size_t)n * HID);
#pragma unroll
        for (int i = 0; i < HID / 4; i++)
            op[i] = make_float4(v[4 * i], v[4 * i + 1], v[4 * i + 2], v[4 * i + 3]);
    }
    // per-block stats partials (no global atomics)
    float msk = valid ? 1.f : 0.f;
    int w = threadIdx.x >> 6;
#pragma unroll 4
    for (int f = 0; f < HID; f++) {
        float s1v = v[f] * msk, s2v = v[f] * v[f] * msk;
        for (int o = 32; o; o >>= 1) {
            s1v += __shfl_down(s1v, o);
            s2v += __shfl_down(s2v, o);
        }
        if ((threadIdx.x & 63) == 0) { red[w][f] = s1v; red[w][HID + f] = s2v; }
    }
    __syncthreads();
    if (threadIdx.x < 2 * HID) {
        int t = threadIdx.x;
        part2[(size_t)blockIdx.x * 64 + t] = red[0][t] + red[1][t] + red[2][t] + red[3][t];
    }
}

// ---------------- fold BN2 ----------------
__global__ void k_params2(const float* __restrict__ part2, const float* __restrict__ g2,
                          const float* __restrict__ be2, float* __restrict__ pPQ) {
    __shared__ double st[64];
    int t = threadIdx.x;  // 64 threads
    double s = 0.0;
    for (int b = 0; b < NB_NODE; b++) s += (double)part2[(size_t)b * 64 + t];
    st[t] = s;
    __syncthreads();
    if (t < HID) {
        double invN = 1.0 / (double)N_NODES;
        double mu = st[t] * invN;
        double var = st[HID + t] * invN - mu * mu;
        double sc = (double)g2[t] / sqrt(var + (double)BN_EPS);
        pPQ[t] = (float)sc;
        pPQ[HID + t] = (float)((double)be2[t] - mu * sc);
    }
}

// ---------------- attentional pooling: block per graph ----------------
#define FIN_TPB 128
__launch_bounds__(FIN_TPB)
__global__ void k_final(const float* __restrict__ h2pre, const int* __restrict__ batch,
                        const float* __restrict__ pPQ, const float* __restrict__ gate_w,
                        const float* __restrict__ gate_b, const float* __restrict__ lin_w,
                        const float* __restrict__ lin_b, float* __restrict__ out) {
    __shared__ int sh_lo, sh_hi;
    __shared__ float red[2][HID + 2];
    __shared__ float sh_P[HID], sh_Q[HID], sh_gw[HID], sh_lw[HID];
    int g = blockIdx.x;
    if (threadIdx.x == 0) {
        int lo = 0, hi = N_NODES;
        while (lo < hi) { int mid = (lo + hi) >> 1; if (batch[mid] < g) lo = mid + 1; else hi = mid; }
        sh_lo = lo;
        int lo2 = lo, hi2 = N_NODES;
        int key2 = g + 1;
        while (lo2 < hi2) { int mid = (lo2 + hi2) >> 1; if (batch[mid] < key2) lo2 = mid + 1; else hi2 = mid; }
        sh_hi = lo2;
    }
    if (threadIdx.x < HID) {
        sh_P[threadIdx.x] = pPQ[threadIdx.x];
        sh_Q[threadIdx.x] = pPQ[HID + threadIdx.x];
        sh_gw[threadIdx.x] = gate_w[threadIdx.x];
        sh_lw[threadIdx.x] = lin_w[threadIdx.x];
    }
    __syncthreads();
    int lo = sh_lo, hi = sh_hi;
    float gb = gate_b[0];

    // pass 1: segment max of gate score
    float mx = -3.0e38f;
    for (int n = lo + threadIdx.x; n < hi; n += FIN_TPB) {
        const float4* hp = (const float4*)(h2pre + (size_t)n * HID);
        float sc = gb;
#pragma unroll
        for (int i = 0; i < HID / 4; i++) {
            float4 v = hp[i];
            sc += relu_f(fmaf(v.x, sh_P[4 * i], sh_Q[4 * i])) * sh_gw[4 * i];
            sc += relu_f(fmaf(v.y, sh_P[4 * i + 1], sh_Q[4 * i + 1])) * sh_gw[4 * i + 1];
            sc += relu_f(fmaf(v.z, sh_P[4 * i + 2], sh_Q[4 * i + 2])) * sh_gw[4 * i + 2];
            sc += relu_f(fmaf(v.w, sh_P[4 * i + 3], sh_Q[4 * i + 3])) * sh_gw[4 * i + 3];
        }
        mx = fmaxf(mx, sc);
    }
    for (int o = 32; o; o >>= 1) mx = fmaxf(mx, __shfl_down(mx, o));
    if ((threadIdx.x & 63) == 0) red[threadIdx.x >> 6][0] = mx;
    __syncthreads();
    float smax = fmaxf(red[0][0], red[1][0]);
    __syncthreads();

    // pass 2: exp-sum and weighted feature sums
    float S = 0.f;
    float T[HID];
#pragma unroll
    for (int f = 0; f < HID; f++) T[f] = 0.f;
    for (int n = lo + threadIdx.x; n < hi; n += FIN_TPB) {
        const float4* hp = (const float4*)(h2pre + (size_t)n * HID);
        float h[HID];
        float sc = gb;
#pragma unroll
        for (int i = 0; i < HID / 4; i++) {
            float4 v = hp[i];
            h[4 * i]     = relu_f(fmaf(v.x, sh_P[4 * i],     sh_Q[4 * i]));
            h[4 * i + 1] = relu_f(fmaf(v.y, sh_P[4 * i + 1], sh_Q[4 * i + 1]));
            h[4 * i + 2] = relu_f(fmaf(v.z, sh_P[4 * i + 2], sh_Q[4 * i + 2]));
            h[4 * i + 3] = relu_f(fmaf(v.w, sh_P[4 * i + 3], sh_Q[4 * i + 3]));
            sc += h[4 * i] * sh_gw[4 * i] + h[4 * i + 1] * sh_gw[4 * i + 1]
                + h[4 * i + 2] * sh_gw[4 * i + 2] + h[4 * i + 3] * sh_gw[4 * i + 3];
        }
        float e = __expf(sc - smax);
        S += e;
#pragma unroll
        for (int f = 0; f < HID; f++) T[f] += e * h[f];
    }
    for (int o = 32; o; o >>= 1) {
        S += __shfl_down(S, o);
#pragma unroll
        for (int f = 0; f < HID; f++) T[f] += __shfl_down(T[f], o);
    }
    if ((threadIdx.x & 63) == 0) {
        int w = threadIdx.x >> 6;
        red[w][1] = S;
#pragma unroll
        for (int f = 0; f < HID; f++) red[w][2 + f] = T[f];
    }
    __syncthreads();
    if (threadIdx.x == 0) {
        float St = red[0][1] + red[1][1];
        float z = lin_b[0];
        if (St > 0.f) {
            float inv = 1.f / St;
#pragma unroll
            for (int f = 0; f < HID; f++)
                z += (red[0][2 + f] + red[1][2 + f]) * inv * sh_lw[f];
        }
        out[g] = 1.f / (1.f + __expf(-z));
    }
}

extern "C" void kernel_launch(void* const* d_in, const int* in_sizes, int n_in,
                              void* d_out, int out_size, void* d_ws, size_t ws_size,
                              hipStream_t stream) {
    const float* x = (const float*)d_in[0];
    const int* ei = (const int*)d_in[1];       // int32 per harness convention
    const int* batch = (const int*)d_in[2];    // int32
    const float* W1l = (const float*)d_in[3];
    const float* b1l = (const float*)d_in[4];
    const float* W1r = (const float*)d_in[5];
    const float* W2l = (const float*)d_in[6];
    const float* b2l = (const float*)d_in[7];
    const float* W2r = (const float*)d_in[8];
    const float* g1 = (const float*)d_in[9];
    const float* be1 = (const float*)d_in[10];
    const float* g2 = (const float*)d_in[11];
    const float* be2 = (const float*)d_in[12];
    const float* gate_w = (const float*)d_in[13];
    const float* gate_b = (const float*)d_in[14];
    const float* lin_w = (const float*)d_in[15];
    const float* lin_b = (const float*)d_in[16];

    const int* srcp = ei;
    const int* dstp = ei + N_EDGES;

    char* ws = (char*)d_ws;
    size_t p = 0;
    auto alloc = [&](size_t bytes) -> char* {
        char* r = ws + p;
        p = (p + bytes + 255) & ~(size_t)255;
        return r;
    };
    // zero-initialized region (one memset covers [0, zbytes))
    int* deg = (int*)alloc((size_t)N_NODES * 4);
    float* sum1 = (float*)alloc((size_t)N_NODES * 4);
    size_t zbytes = p;
    // non-zeroed scratch (fully written each launch)
    int* offsets = (int*)alloc((size_t)(N_NODES + 1) * 4);
    int* cursor = (int*)alloc((size_t)N_NODES * 4);
    float* a = (float*)alloc((size_t)N_NODES * 4);
    float* pABC = (float*)alloc(96 * 4);
    float* pPQ = (float*)alloc(64 * 4);
    float* part1 = (float*)alloc((size_t)NB_NODE * 8 * 4);
    float* part2 = (float*)alloc((size_t)NB_NODE * 64 * 4);
    int nb = (N_NODES + SCAN_EPB - 1) / SCAN_EPB;
    int* bsum = (int*)alloc((size_t)nb * 4);
    int* bbase = (int*)alloc((size_t)nb * 4);
    float* agg2 = (float*)alloc((size_t)N_NODES * HID * 4);
    int* csr = (int*)alloc((size_t)N_EDGES * 4);
    float* h2pre = (float*)csr;  // alias: csr (E*4 B) dead before h2pre (N*HID*4 B) is written

    hipMemsetAsync(d_ws, 0, zbytes, stream);

    k_deg<<<(N_EDGES + 255) / 256, 256, 0, stream>>>(dstp, deg);
    k_scan_partial<<<nb, SCAN_TPB, 0, stream>>>(deg, bsum);
    k_scan_bases<<<1, 64, 0, stream>>>(bsum, bbase, nb, offsets);
    k_scan_write<<<nb, SCAN_TPB, 0, stream>>>(deg, bbase, offsets, cursor);
    k_scatter<<<(N_EDGES + 255) / 256, 256, 0, stream>>>(srcp, dstp, x, cursor, csr, sum1);
    k_stats1<<<NB_NODE, 256, 0, stream>>>(offsets, sum1, x, a, part1);
    k_params1<<<1, 64, 0, stream>>>(part1, W1l, b1l, W1r, g1, be1, pABC);
    k_agg2<<<(N_NODES * HID + 255) / 256, 256, 0, stream>>>(offsets, csr, a, x, pABC, agg2);
    k_mm<<<NB_NODE, 256, 0, stream>>>(a, x, agg2, pABC, W2l, W2r, b2l, h2pre, part2);
    k_params2<<<1, 64, 0, stream>>>(part2, g2, be2, pPQ);
    k_final<<<N_GRAPHS, FIN_TPB, 0, stream>>>(h2pre, batch, pPQ, gate_w, gate_b, lin_w, lin_b,
                                              (float*)d_out);
}